// Round 7
// baseline (206.013 us; speedup 1.0000x reference)
//
#include <hip/hip_runtime.h>
#include <hip/hip_bf16.h>
#include <stdint.h>

#define IN_F   4096
#define OUT_F  768
#define OUTB   (OUT_F * 8)       // 6144
#define BATCH  1024
#define SPLITK 8
#define KSPAN  (IN_F / SPLITK)   // 512
#define NS     (KSPAN / 32)      // 16 k32-steps per wave
#define PLANE  (BATCH * OUT_F)   // 786432 floats
#define PLANE4 (PLANE / 4)       // 196608 float4
#define EPIBLK 768

// Fragment-order packs (16B granules), VERIFIED layout (rounds 6):
//   apk granule(m,k8):  idx = ((m>>4)*128 + (k>>5))*64 + (m&15) + 16*((k>>3)&3)
//   bpk granule(n,k8):  idx = ((n>>4)*128 + (k>>5))*64 + (n&15) + 16*((k>>3)&3)
// A frag load for (m16,k32) is ONE coalesced global_load_dwordx4 at base+lane.

// ws layout (bytes):
//   0        : predp float[8][PLANE]   split-K partial planes (25.17 MB)
//   25165824 : bpk   uint4[393216]     B fragment-pack (6.29 MB)
//   31457280 : apk   uint4[524288]     A fragment-pack (8.39 MB)
//   39845888 : regpart float[1536]
//   39852032 : sqpart  float[768]
#define WS_WP    25165824
#define WS_LABF  31457280
#define WS_REGP  39845888
#define WS_SQP   39852032

typedef short short8  __attribute__((ext_vector_type(8)));
typedef float f32x4   __attribute__((ext_vector_type(4)));
typedef unsigned int u32;

__device__ __forceinline__ ushort f2bf(float f) {
    uint32_t u = __builtin_bit_cast(uint32_t, f);
    u += 0x7FFFu + ((u >> 16) & 1u);
    return (ushort)(u >> 16);
}

__device__ __forceinline__ float waveReduceSum(float v) {
    #pragma unroll
    for (int off = 32; off > 0; off >>= 1) v += __shfl_down(v, off, 64);
    return v;
}

// k_weights: blocks [0,1536): int_weights -> bpk fragment-pack + reg partials.
// blocks [1536,2560): latent fp32->bf16 -> apk fragment-pack.
__global__ __launch_bounds__(256) void k_weights(const float* __restrict__ w,
                                                 const float* __restrict__ latent,
                                                 uint4* __restrict__ bpk,
                                                 uint4* __restrict__ apk,
                                                 float* __restrict__ regpart) {
    if (blockIdx.x >= 1536) {
        // latent pack: thread -> (m, kk) with kk = 16-col pair index in [0,256)
        int t2 = (blockIdx.x - 1536) * 256 + threadIdx.x;   // [0, 262144)
        int q  = t2 >> 4;
        int kk = q & 255;            // which 16-float column chunk
        int mg = q >> 8;             // m16 group [0,64)
        int m  = (mg << 4) | (t2 & 15);
        const float4* lrow = (const float4*)(latent + (size_t)m * IN_F + kk * 16);
        float4 a0 = lrow[0], a1 = lrow[1], a2 = lrow[2], a3 = lrow[3];
        union { ushort u[8]; uint4 v; } g1, g2;
        g1.u[0]=f2bf(a0.x); g1.u[1]=f2bf(a0.y); g1.u[2]=f2bf(a0.z); g1.u[3]=f2bf(a0.w);
        g1.u[4]=f2bf(a1.x); g1.u[5]=f2bf(a1.y); g1.u[6]=f2bf(a1.z); g1.u[7]=f2bf(a1.w);
        g2.u[0]=f2bf(a2.x); g2.u[1]=f2bf(a2.y); g2.u[2]=f2bf(a2.z); g2.u[3]=f2bf(a2.w);
        g2.u[4]=f2bf(a3.x); g2.u[5]=f2bf(a3.y); g2.u[6]=f2bf(a3.z); g2.u[7]=f2bf(a3.w);
        // k8 = 2kk, 2kk+1 -> same k32 plane (kk>>1); slots 16 apart
        uint4* dst = apk + (size_t)(mg * 128 + (kk >> 1)) * 64
                         + (t2 & 15) + 32 * (kk & 1);
        dst[0]  = g1.v;
        dst[16] = g2.v;
        return;
    }

    int t  = blockIdx.x * 256 + threadIdx.x;
    int o  = t % OUT_F;          // n
    int i8 = t / OUT_F;          // k8 in [0,512)
    const float* src = w + (size_t)(i8 * 8) * OUTB + (size_t)o * 8;

    const float P[8] = {1.f, 2.f, 4.f, 8.f, 16.f, 32.f, 64.f, -128.f};
    float regsum = 0.f;
    union { ushort u[8]; uint4 v; } pk;

    #pragma unroll
    for (int r = 0; r < 8; r++) {
        float4 a = *(const float4*)(src + (size_t)r * OUTB);
        float4 b = *(const float4*)(src + (size_t)r * OUTB + 4);
        float x[8] = {a.x, a.y, a.z, a.w, b.x, b.y, b.z, b.w};
        float iw = 0.f;
        #pragma unroll
        for (int j = 0; j < 8; j++) {
            float p = __builtin_amdgcn_rcpf(1.f + __expf(-x[j]));
            iw += p * P[j];
            regsum += fminf(p, 1.f - p);
        }
        pk.u[r] = f2bf(iw);      // int_weights[k=8*i8+r][n=o]
    }
    bpk[(size_t)((o >> 4) * 128 + (i8 >> 2)) * 64 + (o & 15) + ((i8 & 3) << 4)] = pk.v;

    float ws = waveReduceSum(regsum);
    __shared__ float red[4];
    int lane = threadIdx.x & 63, wv = threadIdx.x >> 6;
    if (lane == 0) red[wv] = ws;
    __syncthreads();
    if (threadIdx.x == 0) regpart[blockIdx.x] = red[0] + red[1] + red[2] + red[3];
}

// k_gemm: LDS-free split-K=8 bf16 MFMA GEMM, XCD-pinned. 1-D grid of 768
// blocks x 128 thr (3 blocks/CU balanced, 6 waves/CU, 1.5 waves/SIMD).
// Decode: bz = d&7 -> each XCD owns ONE split-K slice; its working set
// (apk k-slice 2.1MB + bpk k-slice 0.8MB) fits the 4MB XCD L2, so fragment
// loads are L2-hits after first touch (placement heuristic only — any
// mapping is correct). Each wave owns a 64x64 tile (acc[4][4]); fragments
// loaded directly global->VGPR (one dwordx4 each), depth-4 register
// pipeline, no LDS, no barriers. Pure disjoint plane stores — NO atomics.
__global__ __launch_bounds__(128) void k_gemm(const uint4* __restrict__ apk,
                                              const uint4* __restrict__ bpk,
                                              float* __restrict__ predp) {
    const int tid  = threadIdx.x;
    const int lane = tid & 63, w = tid >> 6;
    const int d    = blockIdx.x;
    const int bz   = d & 7;                 // XCD-pinned split-K slice
    const int s9   = d >> 3;                // [0,96)
    const int n0   = (s9 % 12) * 64;
    const int m0   = (s9 / 12) * 128 + w * 64;
    const int kb32 = bz * (KSPAN >> 5);     // 16 k32-planes per slice

    const uint4* Ag = apk + (size_t)((m0 >> 4) * 128 + kb32) * 64 + lane;
    const uint4* Bg = bpk + (size_t)((n0 >> 4) * 128 + kb32) * 64 + lane;

    f32x4 acc[4][4] = {};
    uint4 af[4][4], bf[4][4];   // [set][frag] — all indices compile-time

    #define ISSUE(SET, S) do {                                        \
        _Pragma("unroll")                                             \
        for (int i = 0; i < 4; ++i) {                                 \
            af[SET][i] = Ag[i * 8192 + (S) * 64];                     \
            bf[SET][i] = Bg[i * 8192 + (S) * 64];                     \
        }                                                             \
    } while (0)

    #define MM(SET) do {                                              \
        _Pragma("unroll")                                             \
        for (int i = 0; i < 4; ++i)                                   \
        _Pragma("unroll")                                             \
        for (int j = 0; j < 4; ++j)                                   \
            acc[i][j] = __builtin_amdgcn_mfma_f32_16x16x32_bf16(      \
                __builtin_bit_cast(short8, af[SET][i]),               \
                __builtin_bit_cast(short8, bf[SET][j]),               \
                acc[i][j], 0, 0, 0);                                  \
    } while (0)

    ISSUE(0, 0); ISSUE(1, 1); ISSUE(2, 2); ISSUE(3, 3);
    for (int s = 0; s < NS - 4; s += 4) {      // s = 0,4,8 (NS=16)
        MM(0); ISSUE(0, s + 4);
        MM(1); ISSUE(1, s + 5);
        MM(2); ISSUE(2, s + 6);
        MM(3); ISSUE(3, s + 7);
    }
    MM(0); MM(1); MM(2); MM(3);
    #undef ISSUE
    #undef MM

    const int quad = lane >> 4, l16 = lane & 15;
    float* plane = predp + (size_t)bz * PLANE;
    #pragma unroll
    for (int i = 0; i < 4; i++)
    #pragma unroll
    for (int j = 0; j < 4; j++)
    #pragma unroll
    for (int r = 0; r < 4; r++) {
        int m = m0 + i * 16 + quad * 4 + r;
        int n = n0 + j * 16 + l16;
        plane[(size_t)m * OUT_F + n] = acc[i][j][r];
    }
}

// k_epi: 768 blocks x 256 threads; thread -> 4 consecutive n (one float4 per
// plane, 128B contiguous tsum). Per-block partial -> plain store. NO atomics.
__global__ __launch_bounds__(256) void k_epi(const float* __restrict__ predp,
                                             const float* __restrict__ tsum,
                                             float* __restrict__ sqpart) {
    int g = blockIdx.x * 256 + threadIdx.x;     // float4 index in [0, 196608)
    int m = g / (OUT_F / 4);
    int c = g % (OUT_F / 4);
    const float4* pp = (const float4*)predp;
    float pv[4] = {0.f, 0.f, 0.f, 0.f};
    #pragma unroll
    for (int p = 0; p < SPLITK; p++) {
        float4 q = pp[g + p * PLANE4];
        pv[0] += q.x; pv[1] += q.y; pv[2] += q.z; pv[3] += q.w;
    }
    const float* ts = tsum + (size_t)m * OUTB + (size_t)c * 32;
    float lsum = 0.f;
    #pragma unroll
    for (int j = 0; j < 4; j++) {
        float4 t0 = *(const float4*)(ts + j * 8);
        float4 t1 = *(const float4*)(ts + j * 8 + 4);
        float isum = t0.x + 2.f * t0.y + 4.f * t0.z + 8.f * t0.w
                   + 16.f * t1.x + 32.f * t1.y + 64.f * t1.z - 128.f * t1.w;
        float d = pv[j] - isum;
        lsum += d * d;
    }
    float wsum = waveReduceSum(lsum);
    __shared__ float red[4];
    if ((threadIdx.x & 63) == 0) red[threadIdx.x >> 6] = wsum;
    __syncthreads();
    if (threadIdx.x == 0)
        sqpart[blockIdx.x] = red[0] + red[1] + red[2] + red[3];
}

// k_fin: 1 block; reduce regpart[1536] + sqpart[768], write the 3 outputs.
__global__ __launch_bounds__(256) void k_fin(const float* __restrict__ regpart,
                                             const float* __restrict__ sqpart,
                                             float* __restrict__ out) {
    int tid = threadIdx.x;
    float r = 0.f, s = 0.f;
    #pragma unroll
    for (int j = 0; j < 6; j++) r += regpart[tid + j * 256];
    #pragma unroll
    for (int j = 0; j < 3; j++) s += sqpart[tid + j * 256];
    r = waveReduceSum(r);
    s = waveReduceSum(s);
    __shared__ float redR[4], redS[4];
    int lane = tid & 63, wv = tid >> 6;
    if (lane == 0) { redR[wv] = r; redS[wv] = s; }
    __syncthreads();
    if (tid == 0) {
        float R = redR[0] + redR[1] + redR[2] + redR[3];
        float S = redS[0] + redS[1] + redS[2] + redS[3];
        float recon = S / ((float)(BATCH * OUT_F) * 255.f * 255.f);
        float reg   = 0.001f * R / (float)((size_t)IN_F * OUTB);
        out[0] = recon + reg;
        out[1] = recon;
        out[2] = reg;
    }
}

extern "C" void kernel_launch(void* const* d_in, const int* in_sizes, int n_in,
                              void* d_out, int out_size, void* d_ws, size_t ws_size,
                              hipStream_t stream) {
    const float* latent = (const float*)d_in[0];   // [1024, 4096]
    const float* tsum   = (const float*)d_in[1];   // [1024, 6144]
    const float* weight = (const float*)d_in[2];   // [4096, 6144]
    float* out      = (float*)d_out;
    float* predp    = (float*)d_ws;
    uint4* bpk      = (uint4*)((char*)d_ws + WS_WP);
    uint4* apk      = (uint4*)((char*)d_ws + WS_LABF);
    float* regpart  = (float*)((char*)d_ws + WS_REGP);
    float* sqpart   = (float*)((char*)d_ws + WS_SQP);

    k_weights<<<2560, 256, 0, stream>>>(weight, latent, bpk, apk, regpart);
    k_gemm<<<768, 128, 0, stream>>>(apk, bpk, predp);
    k_epi<<<EPIBLK, 256, 0, stream>>>(predp, tsum, sqpart);
    k_fin<<<1, 256, 0, stream>>>(regpart, sqpart, out);
}

// Round 8
// 197.794 us; speedup vs baseline: 1.0416x; 1.0416x over previous
//
#include <hip/hip_runtime.h>
#include <hip/hip_bf16.h>
#include <stdint.h>

#define IN_F   4096
#define OUT_F  768
#define OUTB   (OUT_F * 8)       // 6144
#define BATCH  1024
#define SPLITK 8
#define KSPAN  (IN_F / SPLITK)   // 512
#define KSTEP  32
#define NIT    (KSPAN / KSTEP)   // 16
#define TN     192
#define TM     128
#define PLANE  (BATCH * OUT_F)   // 786432 floats
#define PLANE4 (PLANE / 4)       // 196608 float4
#define EPIBLK 768

// ws layout (bytes):
//   0        : predp float[8][PLANE]   split-K partial planes (25.17 MB)
//   25165824 : wp    ushort[IN_F*OUT_F]  packed [(k/8)][n][k%8]  (6.29 MB)
//   31457280 : labf  ushort[BATCH*IN_F]  bf16 latent row-major   (8.39 MB)
//   39845888 : regpart float[1536]
//   39852032 : sqpart  float[768]
#define WS_WP    25165824
#define WS_LABF  31457280
#define WS_REGP  39845888
#define WS_SQP   39852032

typedef short short8  __attribute__((ext_vector_type(8)));
typedef float f32x4   __attribute__((ext_vector_type(4)));
typedef unsigned int u32;

__device__ __forceinline__ ushort f2bf(float f) {
    uint32_t u = __builtin_bit_cast(uint32_t, f);
    u += 0x7FFFu + ((u >> 16) & 1u);
    return (ushort)(u >> 16);
}

__device__ __forceinline__ float waveReduceSum(float v) {
    #pragma unroll
    for (int off = 32; off > 0; off >>= 1) v += __shfl_down(v, off, 64);
    return v;
}

__device__ __forceinline__ void glds16(const void* g, void* l) {
    __builtin_amdgcn_global_load_lds(
        (const __attribute__((address_space(1))) u32*)g,
        (__attribute__((address_space(3))) u32*)l, 16, 0, 0);
}

// k_weights: blocks [0,1536): int_weights (bf16 packed [(k/8)][n][k%8]) + reg
// partials. blocks [1536,2048): latent fp32->bf16 conversion (rides along).
__global__ __launch_bounds__(256) void k_weights(const float* __restrict__ w,
                                                 const float* __restrict__ latent,
                                                 ushort* __restrict__ wp,
                                                 ushort* __restrict__ labf,
                                                 float* __restrict__ regpart) {
    if (blockIdx.x >= 1536) {
        int t = (blockIdx.x - 1536) * 256 + threadIdx.x;
        const float4* src = (const float4*)latent;
        uint4* dst = (uint4*)labf;
        #pragma unroll
        for (int j = 0; j < 4; j++) {
            int o = j * 131072 + t;
            float4 a0 = src[2 * o];
            float4 a1 = src[2 * o + 1];
            union { ushort u[8]; uint4 v; } pk;
            pk.u[0] = f2bf(a0.x); pk.u[1] = f2bf(a0.y); pk.u[2] = f2bf(a0.z); pk.u[3] = f2bf(a0.w);
            pk.u[4] = f2bf(a1.x); pk.u[5] = f2bf(a1.y); pk.u[6] = f2bf(a1.z); pk.u[7] = f2bf(a1.w);
            dst[o] = pk.v;
        }
        return;
    }

    int t  = blockIdx.x * 256 + threadIdx.x;
    int o  = t % OUT_F;
    int i8 = t / OUT_F;
    const float* src = w + (size_t)(i8 * 8) * OUTB + (size_t)o * 8;

    const float P[8] = {1.f, 2.f, 4.f, 8.f, 16.f, 32.f, 64.f, -128.f};
    float regsum = 0.f;
    union { ushort u[8]; uint4 v; } pk;

    #pragma unroll
    for (int r = 0; r < 8; r++) {
        float4 a = *(const float4*)(src + (size_t)r * OUTB);
        float4 b = *(const float4*)(src + (size_t)r * OUTB + 4);
        float x[8] = {a.x, a.y, a.z, a.w, b.x, b.y, b.z, b.w};
        float iw = 0.f;
        #pragma unroll
        for (int j = 0; j < 8; j++) {
            float p = __builtin_amdgcn_rcpf(1.f + __expf(-x[j]));
            iw += p * P[j];
            regsum += fminf(p, 1.f - p);
        }
        pk.u[r] = f2bf(iw);
    }
    *(uint4*)(wp + ((size_t)i8 * OUT_F + o) * 8) = pk.v;

    float ws = waveReduceSum(regsum);
    __shared__ float red[4];
    int lane = threadIdx.x & 63, wv = threadIdx.x >> 6;
    if (lane == 0) red[wv] = ws;
    __syncthreads();
    if (threadIdx.x == 0) regpart[blockIdx.x] = red[0] + red[1] + red[2] + red[3];
}

// k_gemm: split-K=8 bf16 MFMA GEMM, 192x128 block tile (HBM demand 84 MB vs
// 201 MB at 64-wide tiles — the round-8 lever). Grid 4x8x8 = 256 blocks =
// exactly 1/CU, 384 thr = 6 waves; each wave owns a 64x64 sub-tile
// (acc[4][4], reads/MFMA = 0.5). K_STEP=32, triple-buffered counted-vmcnt
// pipeline (R5-proven): waves 0-1 stage the 8 A-planes, waves 2-5 stage the
// 12 B-planes (3 = one kg each); per-wave s_waitcnt vmcnt(4/3), never 0 in
// the main loop. 64B A-rows -> natural bank spread, no swizzle needed.
// Pure disjoint plane stores — NO fences/atomics.
__global__ __launch_bounds__(384) void k_gemm(const ushort* __restrict__ labf,
                                              const ushort* __restrict__ wp,
                                              float* __restrict__ predp) {
    __shared__ __align__(16) ushort lA[3][8 * 512];   // [buf][row*32 + g*8]  128r x 32k
    __shared__ __align__(16) ushort lB[3][12 * 512];  // [buf][(kg*3+h)*512 + n*8]

    const int tid  = threadIdx.x;
    const int lane = tid & 63, w = tid >> 6;          // w in 0..5
    const int n0   = blockIdx.x * TN;
    const int m0   = blockIdx.y * TM;
    const int bz   = blockIdx.z;
    const int kbase = bz * KSPAN;
    const int kg0   = kbase >> 3;
    const int quad = lane >> 4, l16 = lane & 15;
    const int wmh = w & 1;            // m-half   (0..1) -> rows  m0 + 64*wmh
    const int wnt = w >> 1;           // n-third  (0..2) -> cols  n0 + 64*wnt

    f32x4 acc[4][4] = {};

    // staging geometry (per wave, wave-uniform)
    const int r4 = lane >> 2, c4 = lane & 3;          // A: row-in-plane, granule
    const int kgw = w - 2;                            // B: kg owned by waves 2..5

    #define STAGE(bi, it_) do {                                                        \
        if (w < 2) {                                                                   \
            _Pragma("unroll")                                                          \
            for (int k = 0; k < 4; ++k) {                                              \
                int p = 4 * w + k;                                                     \
                glds16(labf + (size_t)(m0 + 16 * p + r4) * IN_F                        \
                            + kbase + (it_) * KSTEP + c4 * 8,                          \
                       &lA[bi][p * 512]);                                              \
            }                                                                          \
        } else {                                                                       \
            _Pragma("unroll")                                                          \
            for (int h = 0; h < 3; ++h) {                                              \
                glds16(wp + ((size_t)(kg0 + (it_) * 4 + kgw) * OUT_F                   \
                             + n0 + h * 64 + lane) * 8,                                \
                       &lB[bi][(kgw * 3 + h) * 512]);                                  \
            }                                                                          \
        }                                                                              \
    } while (0)

    #define WAITOWN() do {                                                             \
        if (w < 2) asm volatile("s_waitcnt vmcnt(4)" ::: "memory");                    \
        else       asm volatile("s_waitcnt vmcnt(3)" ::: "memory");                    \
    } while (0)

    #define MSTEP(bi) do {                                                             \
        short8 af[4], bf[4];                                                           \
        _Pragma("unroll")                                                              \
        for (int i = 0; i < 4; ++i)                                                    \
            af[i] = *(const short8*)&lA[bi][(wmh * 64 + i * 16 + l16) * 32 + quad * 8];\
        _Pragma("unroll")                                                              \
        for (int j = 0; j < 4; ++j)                                                    \
            bf[j] = *(const short8*)&lB[bi][(quad * 3 + wnt) * 512 + (j * 16 + l16) * 8];\
        _Pragma("unroll")                                                              \
        for (int i = 0; i < 4; ++i)                                                    \
        _Pragma("unroll")                                                              \
        for (int j = 0; j < 4; ++j)                                                    \
            acc[i][j] = __builtin_amdgcn_mfma_f32_16x16x32_bf16(af[i], bf[j],          \
                                                                acc[i][j], 0, 0, 0);   \
    } while (0)

    // prologue: tiles 0 and 1 in flight; wait only own tile-0 loads.
    STAGE(0, 0);
    STAGE(1, 1);
    WAITOWN();
    __builtin_amdgcn_s_barrier();
    __builtin_amdgcn_sched_barrier(0);

    int bR = 0, bW = 2;
    for (int it = 0; it < NIT - 2; ++it) {
        STAGE(bW, it + 2);               // depth-2 prefetch
        MSTEP(bR);
        WAITOWN();                       // own it+1 loads done; it+2 stay in flight
        __builtin_amdgcn_s_barrier();
        __builtin_amdgcn_sched_barrier(0);
        bR = (bR + 1 == 3) ? 0 : bR + 1;
        bW = (bW + 1 == 3) ? 0 : bW + 1;
    }
    // tail: tile NIT-2 (drain all), then tile NIT-1
    MSTEP(bR);
    asm volatile("s_waitcnt vmcnt(0)" ::: "memory");
    __builtin_amdgcn_s_barrier();
    __builtin_amdgcn_sched_barrier(0);
    bR = (bR + 1 == 3) ? 0 : bR + 1;
    MSTEP(bR);

    #undef STAGE
    #undef WAITOWN
    #undef MSTEP

    float* plane = predp + (size_t)bz * PLANE;
    #pragma unroll
    for (int i = 0; i < 4; i++)
    #pragma unroll
    for (int j = 0; j < 4; j++)
    #pragma unroll
    for (int r = 0; r < 4; r++) {
        int m = m0 + wmh * 64 + i * 16 + quad * 4 + r;
        int n = n0 + wnt * 64 + j * 16 + l16;
        plane[(size_t)m * OUT_F + n] = acc[i][j][r];
    }
}

// k_epi: 768 blocks x 256 threads; sums the 8 split-K planes, squared error
// vs tsum, per-block partial -> plain store. NO atomics.
__global__ __launch_bounds__(256) void k_epi(const float* __restrict__ predp,
                                             const float* __restrict__ tsum,
                                             float* __restrict__ sqpart) {
    int g = blockIdx.x * 256 + threadIdx.x;     // float4 index in [0, 196608)
    int m = g / (OUT_F / 4);
    int c = g % (OUT_F / 4);
    const float4* pp = (const float4*)predp;
    float pv[4] = {0.f, 0.f, 0.f, 0.f};
    #pragma unroll
    for (int p = 0; p < SPLITK; p++) {
        float4 q = pp[g + p * PLANE4];
        pv[0] += q.x; pv[1] += q.y; pv[2] += q.z; pv[3] += q.w;
    }
    const float* ts = tsum + (size_t)m * OUTB + (size_t)c * 32;
    float lsum = 0.f;
    #pragma unroll
    for (int j = 0; j < 4; j++) {
        float4 t0 = *(const float4*)(ts + j * 8);
        float4 t1 = *(const float4*)(ts + j * 8 + 4);
        float isum = t0.x + 2.f * t0.y + 4.f * t0.z + 8.f * t0.w
                   + 16.f * t1.x + 32.f * t1.y + 64.f * t1.z - 128.f * t1.w;
        float d = pv[j] - isum;
        lsum += d * d;
    }
    float wsum = waveReduceSum(lsum);
    __shared__ float red[4];
    if ((threadIdx.x & 63) == 0) red[threadIdx.x >> 6] = wsum;
    __syncthreads();
    if (threadIdx.x == 0)
        sqpart[blockIdx.x] = red[0] + red[1] + red[2] + red[3];
}

// k_fin: 1 block; reduce regpart[1536] + sqpart[768], write the 3 outputs.
__global__ __launch_bounds__(256) void k_fin(const float* __restrict__ regpart,
                                             const float* __restrict__ sqpart,
                                             float* __restrict__ out) {
    int tid = threadIdx.x;
    float r = 0.f, s = 0.f;
    #pragma unroll
    for (int j = 0; j < 6; j++) r += regpart[tid + j * 256];
    #pragma unroll
    for (int j = 0; j < 3; j++) s += sqpart[tid + j * 256];
    r = waveReduceSum(r);
    s = waveReduceSum(s);
    __shared__ float redR[4], redS[4];
    int lane = tid & 63, wv = tid >> 6;
    if (lane == 0) { redR[wv] = r; redS[wv] = s; }
    __syncthreads();
    if (tid == 0) {
        float R = redR[0] + redR[1] + redR[2] + redR[3];
        float S = redS[0] + redS[1] + redS[2] + redS[3];
        float recon = S / ((float)(BATCH * OUT_F) * 255.f * 255.f);
        float reg   = 0.001f * R / (float)((size_t)IN_F * OUTB);
        out[0] = recon + reg;
        out[1] = recon;
        out[2] = reg;
    }
}

extern "C" void kernel_launch(void* const* d_in, const int* in_sizes, int n_in,
                              void* d_out, int out_size, void* d_ws, size_t ws_size,
                              hipStream_t stream) {
    const float* latent = (const float*)d_in[0];   // [1024, 4096]
    const float* tsum   = (const float*)d_in[1];   // [1024, 6144]
    const float* weight = (const float*)d_in[2];   // [4096, 6144]
    float* out      = (float*)d_out;
    float* predp    = (float*)d_ws;
    ushort* wp      = (ushort*)((char*)d_ws + WS_WP);
    ushort* labf    = (ushort*)((char*)d_ws + WS_LABF);
    float* regpart  = (float*)((char*)d_ws + WS_REGP);
    float* sqpart   = (float*)((char*)d_ws + WS_SQP);

    k_weights<<<2048, 256, 0, stream>>>(weight, latent, wp, labf, regpart);
    k_gemm<<<dim3(OUT_F / TN, BATCH / TM, SPLITK), 384, 0, stream>>>(labf, wp, predp);
    k_epi<<<EPIBLK, 256, 0, stream>>>(predp, tsum, sqpart);
    k_fin<<<1, 256, 0, stream>>>(regpart, sqpart, out);
}